// Round 6
// baseline (347.550 us; speedup 1.0000x reference)
//
#include <hip/hip_runtime.h>
#include <hip/hip_bf16.h>
#include <math.h>

#define B 128
#define S 1024
#define H 768
#define NH 8
#define DH 96
#define FUSED 2312
#define FPAD 2432            // fused row stride, padded to 19*128
#define KSPLIT 19
#define KCHUNK 128
#define ASL 8                // aspq slices
#define NSL 8                // flash slices per sample
#define CH 12                // rows per flash chunk (one per wave)
#define SCALE 0.10206207261596575f  // 1/sqrt(96)
#define GELU_C 0.70710678118654752f

__device__ __forceinline__ float dot4(float4 a, float4 b) {
    return a.x * b.x + a.y * b.y + a.z * b.z + a.w * b.w;
}

// ---------------------------------------------------------------------------
// K1: asp_query partials. grid (B, ASL), 192 threads (float4 cols).
// ---------------------------------------------------------------------------
__global__ void aspq_part_kernel(const float* __restrict__ lh,
                                 const int* __restrict__ sep1,
                                 const int* __restrict__ sep2,
                                 float* __restrict__ aspp) {
    int b = blockIdx.x, z = blockIdx.y, t = threadIdx.x;
    int s1 = sep1[b], s2 = sep2[b];
    int lo, hi;
    if (s2 > s1 + 1) { lo = s1 + 1; hi = s2; } else { lo = 0; hi = 1; }
    const float* base = lh + ((size_t)b * S) * H + 4 * t;
    float4 a = {0.f, 0.f, 0.f, 0.f};
    for (int s = lo + z; s < hi; s += ASL) {
        float4 r = *(const float4*)(base + (size_t)s * H);
        a.x += r.x; a.y += r.y; a.z += r.z; a.w += r.w;
    }
    *(float4*)(aspp + (size_t)z * (B * H) + b * H + 4 * t) = a;
}

// ---------------------------------------------------------------------------
// K2: qu — merge aspq partials; q_h = aspq @ wq_h.T + bq_h; U = q_h @ wk_h.
// grid (B, NH), 256 threads. Block h==0 also writes merged aspq (for fuse).
// ---------------------------------------------------------------------------
__global__ void qu_kernel(const float* __restrict__ aspp,
                          const int* __restrict__ sep1,
                          const int* __restrict__ sep2,
                          const float* __restrict__ wq,
                          const float* __restrict__ bq,
                          const float* __restrict__ wk,
                          float* __restrict__ aspq,
                          float* __restrict__ U) {
    int b = blockIdx.x, h = blockIdx.y, t = threadIdx.x;
    int s1 = sep1[b], s2 = sep2[b];
    int lo, hi;
    if (s2 > s1 + 1) { lo = s1 + 1; hi = s2; } else { lo = 0; hi = 1; }
    float inv = 1.0f / (float)(hi - lo);
    __shared__ float aq[H];
    __shared__ float qh[DH];
    for (int c = t; c < H; c += 256) {
        float a = 0.f;
#pragma unroll
        for (int z = 0; z < ASL; ++z)
            a += aspp[(size_t)z * (B * H) + b * H + c];
        a *= inv;
        aq[c] = a;
        if (h == 0) aspq[b * H + c] = a;
    }
    __syncthreads();
    int wave = t >> 6, lane = t & 63;
#pragma unroll
    for (int i = 0; i < 24; ++i) {
        int d = wave * 24 + i;
        const float* wrow = wq + (size_t)(h * DH + d) * H;
        float a = 0.f;
#pragma unroll
        for (int j = 0; j < H / 64; ++j) a += wrow[lane + 64 * j] * aq[lane + 64 * j];
        for (int off = 32; off; off >>= 1) a += __shfl_xor(a, off);
        if (lane == 0) qh[d] = a + bq[h * DH + d];
    }
    __syncthreads();
    float u0 = 0.f, u1 = 0.f, u2 = 0.f;
    for (int d = 0; d < DH; ++d) {
        const float* wrow = wk + (size_t)(h * DH + d) * H;
        float qd = qh[d];
        u0 += qd * wrow[t];
        u1 += qd * wrow[t + 256];
        u2 += qd * wrow[t + 512];
    }
    float* Ub = U + ((size_t)b * NH + h) * H;
    Ub[t] = u0; Ub[t + 256] = u1; Ub[t + 512] = u2;
}

// ---------------------------------------------------------------------------
// K3: flash — scores + online softmax + weighted V-sum, one lh pass.
// grid (B, NSL), 768 threads (12 waves). Slice z owns rows tlo+z+NSL*j.
// Per-thread replicated (m,l) state: all threads compute identical updates
// from the shared score tile -> only 2 barriers per 12-row chunk.
// ---------------------------------------------------------------------------
__global__ __launch_bounds__(768) void flash_kernel(
        const float* __restrict__ lhg,
        const float* __restrict__ U,
        const int* __restrict__ sep1,
        float* __restrict__ Op,     // [NSL][B][NH][H]
        float* __restrict__ mlb) {  // [NSL][B][NH][2]
    int b = blockIdx.x, z = blockIdx.y, t = threadIdx.x;
    int wave = t >> 6, lane = t & 63;
    int s1 = sep1[b];
    int tlo = (s1 > 1) ? 1 : 0;
    int thi = (s1 > 1) ? s1 : 1;
    int span = thi - tlo;
    int nrows = (span > z) ? ((span - z - 1) / NSL + 1) : 0;

    __shared__ float4 Us[NH * 192];   // 24 KB
    __shared__ float lhs[CH][H];      // 36 KB
    __shared__ float sc[CH][NH];

    const float4* Ub = (const float4*)(U + (size_t)b * NH * H);
    for (int i = t; i < NH * 192; i += 768) Us[i] = Ub[i];
    float Oa[NH], mreg[NH], lreg[NH];
#pragma unroll
    for (int h = 0; h < NH; ++h) { Oa[h] = 0.f; mreg[h] = -1e30f; lreg[h] = 0.f; }
    __syncthreads();

    for (int j0 = 0; j0 < nrows; j0 += CH) {
        int nv = min(CH, nrows - j0);
        if (wave < nv) {
            int s = tlo + z + NSL * (j0 + wave);
            const float4* row = (const float4*)(lhg + ((size_t)b * S + s) * H);
            float4 x0 = row[lane], x1 = row[lane + 64], x2 = row[lane + 128];
            ((float4*)lhs[wave])[lane]       = x0;
            ((float4*)lhs[wave])[lane + 64]  = x1;
            ((float4*)lhs[wave])[lane + 128] = x2;
            float acc[NH];
#pragma unroll
            for (int h = 0; h < NH; ++h) {
                acc[h] = dot4(x0, Us[h * 192 + lane])
                       + dot4(x1, Us[h * 192 + lane + 64])
                       + dot4(x2, Us[h * 192 + lane + 128]);
            }
#pragma unroll
            for (int h = 0; h < NH; ++h) {
                float v = acc[h];
                for (int off = 32; off; off >>= 1) v += __shfl_xor(v, off);
                if (lane == h) sc[wave][h] = v * SCALE;
            }
        } else if (lane < NH) {
            sc[wave][lane] = -1e30f;
        }
        __syncthreads();
        // replicated online-softmax update (identical in every thread)
#pragma unroll
        for (int h = 0; h < NH; ++h) {
            float mx = sc[0][h];
#pragma unroll
            for (int r = 1; r < CH; ++r) mx = fmaxf(mx, sc[r][h]);
            float mn = fmaxf(mreg[h], mx);
            float rr = __expf(mreg[h] - mn);
            mreg[h] = mn;
            Oa[h] *= rr;
            lreg[h] *= rr;
        }
        for (int r = 0; r < nv; ++r) {
            float x = lhs[r][t];
#pragma unroll
            for (int h = 0; h < NH; ++h) {
                float p = __expf(sc[r][h] - mreg[h]);
                Oa[h] += p * x;
                lreg[h] += p;
            }
        }
        __syncthreads();
    }
    float* Ob = Op + (((size_t)z * B + b) * NH) * H;
#pragma unroll
    for (int h = 0; h < NH; ++h) Ob[h * H + t] = Oa[h];
    if (t < NH) {
        float* ml = mlb + ((size_t)z * B + b) * NH * 2;
        ml[2 * t]     = mreg[t];
        ml[2 * t + 1] = lreg[t];
    }
}

// ---------------------------------------------------------------------------
// K4: mergectx — merge flash slices -> wsum (LDS); ctx_h = wv_h @ wsum + bv.
// grid (B, NH), 256 threads.
// ---------------------------------------------------------------------------
__global__ void mergectx_kernel(const float* __restrict__ Op,
                                const float* __restrict__ mlb,
                                const float* __restrict__ wv,
                                const float* __restrict__ bv,
                                float* __restrict__ ctx) {
    int b = blockIdx.x, h = blockIdx.y, t = threadIdx.x;
    float M = -1e30f;
#pragma unroll
    for (int z = 0; z < NSL; ++z)
        M = fmaxf(M, mlb[(((size_t)z * B + b) * NH + t % NH) * 2]);  // dummy to keep uniform? no
    // NOTE: recompute properly below (replicated, cheap)
    M = -1e30f;
#pragma unroll
    for (int z = 0; z < NSL; ++z)
        M = fmaxf(M, mlb[(((size_t)z * B + b) * NH + h) * 2]);
    float wz[NSL], L = 0.f;
#pragma unroll
    for (int z = 0; z < NSL; ++z) {
        const float* ml = mlb + (((size_t)z * B + b) * NH + h) * 2;
        float e = __expf(ml[0] - M);
        wz[z] = e;
        L += e * ml[1];
    }
    float Li = 1.0f / L;
    __shared__ float wsum[H];
    for (int c = t; c < H; c += 256) {
        float a = 0.f;
#pragma unroll
        for (int z = 0; z < NSL; ++z)
            a += wz[z] * Op[(((size_t)z * B + b) * NH + h) * H + c];
        wsum[c] = a * Li;
    }
    __syncthreads();
    int wave = t >> 6, lane = t & 63;
#pragma unroll
    for (int i = 0; i < 24; ++i) {
        int d = wave * 24 + i;
        const float* wrow = wv + (size_t)(h * DH + d) * H;
        float a = 0.f;
#pragma unroll
        for (int j = 0; j < H / 64; ++j) a += wrow[lane + 64 * j] * wsum[lane + 64 * j];
        for (int off = 32; off; off >>= 1) a += __shfl_xor(a, off);
        if (lane == 0) ctx[b * H + h * DH + d] = a + bv[h * DH + d];
    }
}

// ---------------------------------------------------------------------------
// Generic small fp32 GEMM, float4 loads, 32x32 tiles, z split-K.
// ---------------------------------------------------------------------------
template <int TAG, bool KCL>
__global__ void gemm_kernel(const float* __restrict__ A, int lda, int a_bs,
                            const float* __restrict__ W, int ldw, int w_bs,
                            float* __restrict__ C, int ldc, int c_bs,
                            int M, int N, int K, int kclamp) {
    A += (size_t)blockIdx.z * a_bs;
    W += (size_t)blockIdx.z * w_bs;
    C += (size_t)blockIdx.z * c_bs;
    int kcl = KCL ? (kclamp - (int)blockIdx.z * w_bs) : 0;
    int n0 = blockIdx.x * 32, m0 = blockIdx.y * 32;
    __shared__ float As[32][33];
    __shared__ float Ws[32][33];
    int t = threadIdx.x;
    int tx = t & 31, ty = t >> 5;
    int lr = t >> 3, lc = (t & 7) * 4;
    float acc[4] = {0.f, 0.f, 0.f, 0.f};
    for (int k0 = 0; k0 < K; k0 += 32) {
        {
            float4 a = *(const float4*)(A + (size_t)(m0 + lr) * lda + k0 + lc);
            As[lr][lc] = a.x; As[lr][lc + 1] = a.y;
            As[lr][lc + 2] = a.z; As[lr][lc + 3] = a.w;
        }
        {
            int kk = k0 + lc;
            if (KCL) kk = min(kk, kcl);
            float4 w = *(const float4*)(W + (size_t)(n0 + lr) * ldw + kk);
            Ws[lr][lc] = w.x; Ws[lr][lc + 1] = w.y;
            Ws[lr][lc + 2] = w.z; Ws[lr][lc + 3] = w.w;
        }
        __syncthreads();
#pragma unroll
        for (int kk = 0; kk < 32; ++kk) {
            float wv = Ws[tx][kk];
#pragma unroll
            for (int i = 0; i < 4; ++i)
                acc[i] += As[ty + 8 * i][kk] * wv;
        }
        __syncthreads();
    }
    int n = n0 + tx;
#pragma unroll
    for (int i = 0; i < 4; ++i) {
        int m = m0 + ty + 8 * i;
        C[(size_t)m * ldc + n] = acc[i];
    }
}

// ---------------------------------------------------------------------------
// fuse: fused[b] = [lh[b,0,:], merge(crossp)+out_b, aspq, LN(aro)], zero-pad.
// ---------------------------------------------------------------------------
__global__ void fuse_kernel(const float* __restrict__ lh,
                            const float* __restrict__ crossp,
                            const float* __restrict__ out_b,
                            const float* __restrict__ aspq,
                            const float* __restrict__ aro_f,
                            const float* __restrict__ ln_g,
                            const float* __restrict__ ln_b,
                            float* __restrict__ fused) {
    int b = blockIdx.x, t = threadIdx.x;
    float* fb = fused + (size_t)b * FPAD;
    const float* lhb = lh + (size_t)b * S * H;
    for (int i = t; i < H; i += 256) {
        float cr = out_b[i];
#pragma unroll
        for (int z = 0; z < 6; ++z) cr += crossp[(size_t)z * (B * H) + b * H + i];
        fb[i]         = lhb[i];
        fb[H + i]     = cr;
        fb[2 * H + i] = aspq[b * H + i];
    }
    for (int i = t; i < FPAD - FUSED; i += 256) fb[FUSED + i] = 0.f;
    if (t < 8) {
        const float* af = aro_f + b * 8;
        float mu = 0.f;
#pragma unroll
        for (int j = 0; j < 8; ++j) mu += af[j];
        mu *= 0.125f;
        float var = 0.f;
#pragma unroll
        for (int j = 0; j < 8; ++j) { float d = af[j] - mu; var += d * d; }
        var *= 0.125f;
        fb[3 * H + t] = (af[t] - mu) * rsqrtf(var + 1e-5f) * ln_g[t] + ln_b[t];
    }
}

// ---------------------------------------------------------------------------
// mlp2: reduce hdn1 split-K partials + gelu; hdn2; all 8 head outputs.
// ---------------------------------------------------------------------------
__global__ void mlp2_kernel(const float* __restrict__ hdn1p,
                            const float* __restrict__ fusedb,
                            const float* __restrict__ va_b1,
                            const float* __restrict__ va_w2,
                            const float* __restrict__ va_b2,
                            const float* __restrict__ va_w3,
                            const float* __restrict__ va_b3,
                            const float* __restrict__ pol_w,
                            const float* __restrict__ pol_b,
                            const float* __restrict__ aro_w,
                            const float* __restrict__ aro_b,
                            float* __restrict__ out) {
    int b = blockIdx.x, t = threadIdx.x;
    __shared__ float hs[512];
    __shared__ float h2[128];
    for (int n = t; n < 512; n += 256) {
        float sacc = 0.f;
#pragma unroll
        for (int z = 0; z < KSPLIT; ++z)
            sacc += hdn1p[(size_t)z * (B * 512) + b * 512 + n];
        sacc += va_b1[n];
        hs[n] = 0.5f * sacc * (1.0f + erff(sacc * GELU_C));
    }
    __syncthreads();
    int wave = t >> 6, lane = t & 63;
    for (int i = 0; i < 32; ++i) {
        int n = wave * 32 + i;
        float a = 0.f;
#pragma unroll
        for (int j = 0; j < 8; ++j) {
            int k = lane + 64 * j;
            a += hs[k] * va_w2[(size_t)n * 512 + k];
        }
        for (int off = 32; off; off >>= 1) a += __shfl_xor(a, off);
        if (lane == 0) {
            float x = a + va_b2[n];
            h2[n] = 0.5f * x * (1.0f + erff(x * GELU_C));
        }
    }
    __syncthreads();
    const float* fb = fusedb + (size_t)b * FPAD;
    for (int oi = 0; oi < 2; ++oi) {
        int o = wave * 2 + oi;
        float acc = 0.f, bia;
        float* dst;
        if (o < 2) {
            for (int k = lane; k < 128; k += 64) acc += h2[k] * va_w3[o * 128 + k];
            bia = va_b3[o]; dst = out + b * 2 + o;
        } else if (o < 5) {
            int r = o - 2;
            for (int k = lane; k < FUSED; k += 64) acc += fb[k] * pol_w[(size_t)r * FUSED + k];
            bia = pol_b[r]; dst = out + 256 + b * 3 + r;
        } else {
            int r = o - 5;
            for (int k = lane; k < FUSED; k += 64) acc += fb[k] * aro_w[(size_t)r * FUSED + k];
            bia = aro_b[r]; dst = out + 640 + b * 3 + r;
        }
        for (int off = 32; off; off >>= 1) acc += __shfl_xor(acc, off);
        if (lane == 0) *dst = acc + bia;
    }
}

// ---------------------------------------------------------------------------
extern "C" void kernel_launch(void* const* d_in, const int* in_sizes, int n_in,
                              void* d_out, int out_size, void* d_ws, size_t ws_size,
                              hipStream_t stream) {
    const float* lh    = (const float*)d_in[0];
    const float* aro_f = (const float*)d_in[1];
    const int*   sep1  = (const int*)d_in[2];
    const int*   sep2  = (const int*)d_in[3];
    const float* in_w  = (const float*)d_in[4];
    const float* in_b  = (const float*)d_in[5];
    const float* out_w = (const float*)d_in[6];
    const float* out_b = (const float*)d_in[7];
    const float* ln_g  = (const float*)d_in[8];
    const float* ln_b  = (const float*)d_in[9];
    const float* va_w1 = (const float*)d_in[10];
    const float* va_b1 = (const float*)d_in[11];
    const float* va_w2 = (const float*)d_in[12];
    const float* va_b2 = (const float*)d_in[13];
    const float* va_w3 = (const float*)d_in[14];
    const float* va_b3 = (const float*)d_in[15];
    const float* pol_w = (const float*)d_in[16];
    const float* pol_b = (const float*)d_in[17];
    const float* aro_w = (const float*)d_in[18];
    const float* aro_b = (const float*)d_in[19];
    float* out = (float*)d_out;

    float* ws = (float*)d_ws;
    float* aspp   = ws;                          // ASL*B*H
    float* aspq   = aspp + ASL * B * H;          // B*H
    float* Ubuf   = aspq + B * H;                // B*NH*H
    float* Opb    = Ubuf + B * NH * H;           // NSL*B*NH*H
    float* mlbuf  = Opb + (size_t)NSL * B * NH * H;  // NSL*B*NH*2
    float* ctx    = mlbuf + NSL * B * NH * 2;    // B*H
    float* crossp = ctx + B * H;                 // 6*B*H
    float* fusedb = crossp + 6 * B * H;          // B*FPAD
    float* hdn1p  = fusedb + B * FPAD;           // 19*B*512

    const float* wq = in_w;
    const float* wk = in_w + H * H;
    const float* wv = in_w + 2 * H * H;
    const float* bq = in_b;
    const float* bv = in_b + 2 * H;

    // 1) asp_query partials
    aspq_part_kernel<<<dim3(B, ASL), 192, 0, stream>>>(lh, sep1, sep2, aspp);
    // 2) qu: merge + q + U
    qu_kernel<<<dim3(B, NH), 256, 0, stream>>>(aspp, sep1, sep2, wq, bq, wk,
                                               aspq, Ubuf);
    // 3) flash
    flash_kernel<<<dim3(B, NSL), 768, 0, stream>>>(lh, Ubuf, sep1, Opb, mlbuf);
    // 4) mergectx
    mergectx_kernel<<<dim3(B, NH), 256, 0, stream>>>(Opb, mlbuf, wv, bv, ctx);
    // 5) cross partials = ctx @ out_w.T : split-K 6x128 (merged in fuse)
    gemm_kernel<3, false><<<dim3(24, 4, 6), 256, 0, stream>>>(
        ctx, H, KCHUNK, out_w, H, KCHUNK, crossp, H, B * H, B, H, KCHUNK, 0);
    // 6) fused assembly (+cross merge, +LN, +pad)
    fuse_kernel<<<B, 256, 0, stream>>>(lh, crossp, out_b, aspq, aro_f,
                                       ln_g, ln_b, fusedb);
    // 7) hdn1 split-K partials (19 x 128)
    gemm_kernel<4, true><<<dim3(16, 4, KSPLIT), 256, 0, stream>>>(
        fusedb, FPAD, KCHUNK, va_w1, FUSED, KCHUNK,
        hdn1p, 512, B * 512, B, 512, KCHUNK, FUSED - 4);
    // 8) mlp2: reduce+gelu + hdn2 + heads
    mlp2_kernel<<<B, 256, 0, stream>>>(hdn1p, fusedb, va_b1, va_w2, va_b2,
                                       va_w3, va_b3, pol_w, pol_b,
                                       aro_w, aro_b, out);
}

// Round 7
// 244.911 us; speedup vs baseline: 1.4191x; 1.4191x over previous
//
#include <hip/hip_runtime.h>
#include <hip/hip_bf16.h>
#include <math.h>

#define B 128
#define S 1024
#define H 768
#define NH 8
#define DH 96
#define FUSED 2312
#define FPAD 2432            // fused row stride, padded to 19*128
#define KSPLIT 19
#define KCHUNK 128
#define ASL 8                // aspq slices
#define NSL 8                // flash slices per sample
#define FCH 16               // rows per flash chunk
#define SCALE 0.10206207261596575f  // 1/sqrt(96)
#define GELU_C 0.70710678118654752f

__device__ __forceinline__ float dot4(float4 a, float4 b) {
    return a.x * b.x + a.y * b.y + a.z * b.z + a.w * b.w;
}

// ---------------------------------------------------------------------------
// K1: asp_query partials. grid (B, ASL), 192 threads (float4 cols).
// ---------------------------------------------------------------------------
__global__ void aspq_part_kernel(const float* __restrict__ lh,
                                 const int* __restrict__ sep1,
                                 const int* __restrict__ sep2,
                                 float* __restrict__ aspp) {
    int b = blockIdx.x, z = blockIdx.y, t = threadIdx.x;
    int s1 = sep1[b], s2 = sep2[b];
    int lo, hi;
    if (s2 > s1 + 1) { lo = s1 + 1; hi = s2; } else { lo = 0; hi = 1; }
    const float* base = lh + ((size_t)b * S) * H + 4 * t;
    float4 a = {0.f, 0.f, 0.f, 0.f};
    for (int s = lo + z; s < hi; s += ASL) {
        float4 r = *(const float4*)(base + (size_t)s * H);
        a.x += r.x; a.y += r.y; a.z += r.z; a.w += r.w;
    }
    *(float4*)(aspp + (size_t)z * (B * H) + b * H + 4 * t) = a;
}

// ---------------------------------------------------------------------------
// K2: qu — merge aspq partials; q_h = aspq @ wq_h.T + bq_h; U = q_h @ wk_h.
// grid (B, NH), 256 threads. Block h==0 also writes merged aspq (for fuse).
// ---------------------------------------------------------------------------
__global__ void qu_kernel(const float* __restrict__ aspp,
                          const int* __restrict__ sep1,
                          const int* __restrict__ sep2,
                          const float* __restrict__ wq,
                          const float* __restrict__ bq,
                          const float* __restrict__ wk,
                          float* __restrict__ aspq,
                          float* __restrict__ U) {
    int b = blockIdx.x, h = blockIdx.y, t = threadIdx.x;
    int s1 = sep1[b], s2 = sep2[b];
    int lo, hi;
    if (s2 > s1 + 1) { lo = s1 + 1; hi = s2; } else { lo = 0; hi = 1; }
    float inv = 1.0f / (float)(hi - lo);
    __shared__ float aq[H];
    __shared__ float qh[DH];
    for (int c = t; c < H; c += 256) {
        float a = 0.f;
#pragma unroll
        for (int z = 0; z < ASL; ++z)
            a += aspp[(size_t)z * (B * H) + b * H + c];
        a *= inv;
        aq[c] = a;
        if (h == 0) aspq[b * H + c] = a;
    }
    __syncthreads();
    int wave = t >> 6, lane = t & 63;
#pragma unroll
    for (int i = 0; i < 24; ++i) {
        int d = wave * 24 + i;
        const float* wrow = wq + (size_t)(h * DH + d) * H;
        float a = 0.f;
#pragma unroll
        for (int j = 0; j < H / 64; ++j) a += wrow[lane + 64 * j] * aq[lane + 64 * j];
        for (int off = 32; off; off >>= 1) a += __shfl_xor(a, off);
        if (lane == 0) qh[d] = a + bq[h * DH + d];
    }
    __syncthreads();
    float u0 = 0.f, u1 = 0.f, u2 = 0.f;
    for (int d = 0; d < DH; ++d) {
        const float* wrow = wk + (size_t)(h * DH + d) * H;
        float qd = qh[d];
        u0 += qd * wrow[t];
        u1 += qd * wrow[t + 256];
        u2 += qd * wrow[t + 512];
    }
    float* Ub = U + ((size_t)b * NH + h) * H;
    Ub[t] = u0; Ub[t + 256] = u1; Ub[t + 512] = u2;
}

// ---------------------------------------------------------------------------
// K3: flash — wave-per-head online softmax + weighted V-sum, one lh pass.
// grid (B, NSL), 512 threads (8 waves). Slice z owns rows tlo+z+NSL*j.
// Per chunk: cooperative stage FCH rows -> LDS; barrier; wave h processes
// head h over the staged rows entirely in registers (U_h, O_h as 3 float4).
// ---------------------------------------------------------------------------
__global__ __launch_bounds__(512) void flash_kernel(
        const float* __restrict__ lhg,
        const float* __restrict__ U,
        const int* __restrict__ sep1,
        float* __restrict__ Op,     // [NSL][B][NH][H]
        float* __restrict__ mlb) {  // [NSL][B][NH][2]
    int b = blockIdx.x, z = blockIdx.y, t = threadIdx.x;
    int wave = t >> 6, lane = t & 63;
    int s1 = sep1[b];
    int tlo = (s1 > 1) ? 1 : 0;
    int thi = (s1 > 1) ? s1 : 1;
    int span = thi - tlo;
    int nrows = (span > z) ? ((span - z - 1) / NSL + 1) : 0;

    __shared__ float lhs[FCH][H];   // 48 KB

    const float4* Uh = (const float4*)(U + ((size_t)b * NH + wave) * H);
    float4 u0 = Uh[lane], u1 = Uh[lane + 64], u2 = Uh[lane + 128];
    float4 O0 = {0.f, 0.f, 0.f, 0.f}, O1 = O0, O2 = O0;
    float m = -1e30f, l = 0.f;

    int rid = t >> 5;        // 0..15 (staging row)
    int cid = t & 31;        // 0..31 (staging col group)

    for (int j0 = 0; j0 < nrows; j0 += FCH) {
        int nv = min(FCH, nrows - j0);
        if (rid < nv) {
            int sg = tlo + z + NSL * (j0 + rid);
            const float4* row = (const float4*)(lhg + ((size_t)b * S + sg) * H);
            float4* dst = (float4*)lhs[rid];
#pragma unroll
            for (int k = 0; k < 6; ++k) dst[cid + 32 * k] = row[cid + 32 * k];
        }
        __syncthreads();
        for (int r = 0; r < nv; ++r) {
            const float4* xr = (const float4*)lhs[r];
            float4 x0 = xr[lane], x1 = xr[lane + 64], x2 = xr[lane + 128];
            float s = dot4(u0, x0) + dot4(u1, x1) + dot4(u2, x2);
            for (int off = 32; off; off >>= 1) s += __shfl_xor(s, off);
            s *= SCALE;
            if (s <= m) {            // common path: no rescale
                float p = __expf(s - m);
                l += p;
                O0.x += p * x0.x; O0.y += p * x0.y; O0.z += p * x0.z; O0.w += p * x0.w;
                O1.x += p * x1.x; O1.y += p * x1.y; O1.z += p * x1.z; O1.w += p * x1.w;
                O2.x += p * x2.x; O2.y += p * x2.y; O2.z += p * x2.z; O2.w += p * x2.w;
            } else {                 // max moved: rescale, p == 1
                float c = __expf(m - s);
                m = s;
                l = l * c + 1.0f;
                O0.x = O0.x * c + x0.x; O0.y = O0.y * c + x0.y;
                O0.z = O0.z * c + x0.z; O0.w = O0.w * c + x0.w;
                O1.x = O1.x * c + x1.x; O1.y = O1.y * c + x1.y;
                O1.z = O1.z * c + x1.z; O1.w = O1.w * c + x1.w;
                O2.x = O2.x * c + x2.x; O2.y = O2.y * c + x2.y;
                O2.z = O2.z * c + x2.z; O2.w = O2.w * c + x2.w;
            }
        }
        __syncthreads();
    }
    float4* Ob = (float4*)(Op + (((size_t)z * B + b) * NH + wave) * H);
    Ob[lane] = O0; Ob[lane + 64] = O1; Ob[lane + 128] = O2;
    if (lane == 0) {
        float* ml = mlb + ((size_t)z * B + b) * NH * 2;
        ml[2 * wave]     = m;
        ml[2 * wave + 1] = l;
    }
}

// ---------------------------------------------------------------------------
// K4: mergectx — merge flash slices -> wsum (LDS); ctx_h = wv_h @ wsum + bv.
// grid (B, NH), 256 threads.
// ---------------------------------------------------------------------------
__global__ void mergectx_kernel(const float* __restrict__ Op,
                                const float* __restrict__ mlb,
                                const float* __restrict__ wv,
                                const float* __restrict__ bv,
                                float* __restrict__ ctx) {
    int b = blockIdx.x, h = blockIdx.y, t = threadIdx.x;
    float M = -1e30f;
#pragma unroll
    for (int z = 0; z < NSL; ++z)
        M = fmaxf(M, mlb[(((size_t)z * B + b) * NH + h) * 2]);
    float wz[NSL], L = 0.f;
#pragma unroll
    for (int z = 0; z < NSL; ++z) {
        const float* ml = mlb + (((size_t)z * B + b) * NH + h) * 2;
        float e = __expf(ml[0] - M);
        wz[z] = e;
        L += e * ml[1];
    }
    float Li = 1.0f / L;
    __shared__ float wsum[H];
    for (int c = t; c < H; c += 256) {
        float a = 0.f;
#pragma unroll
        for (int z = 0; z < NSL; ++z)
            a += wz[z] * Op[(((size_t)z * B + b) * NH + h) * H + c];
        wsum[c] = a * Li;
    }
    __syncthreads();
    int wave = t >> 6, lane = t & 63;
#pragma unroll
    for (int i = 0; i < 24; ++i) {
        int d = wave * 24 + i;
        const float* wrow = wv + (size_t)(h * DH + d) * H;
        float a = 0.f;
#pragma unroll
        for (int j = 0; j < H / 64; ++j) a += wrow[lane + 64 * j] * wsum[lane + 64 * j];
        for (int off = 32; off; off >>= 1) a += __shfl_xor(a, off);
        if (lane == 0) ctx[b * H + h * DH + d] = a + bv[h * DH + d];
    }
}

// ---------------------------------------------------------------------------
// Generic small fp32 GEMM, float4 loads, 32x32 tiles, z split-K.
// ---------------------------------------------------------------------------
template <int TAG, bool KCL>
__global__ void gemm_kernel(const float* __restrict__ A, int lda, int a_bs,
                            const float* __restrict__ W, int ldw, int w_bs,
                            float* __restrict__ C, int ldc, int c_bs,
                            int M, int N, int K, int kclamp) {
    A += (size_t)blockIdx.z * a_bs;
    W += (size_t)blockIdx.z * w_bs;
    C += (size_t)blockIdx.z * c_bs;
    int kcl = KCL ? (kclamp - (int)blockIdx.z * w_bs) : 0;
    int n0 = blockIdx.x * 32, m0 = blockIdx.y * 32;
    __shared__ float As[32][33];
    __shared__ float Ws[32][33];
    int t = threadIdx.x;
    int tx = t & 31, ty = t >> 5;
    int lr = t >> 3, lc = (t & 7) * 4;
    float acc[4] = {0.f, 0.f, 0.f, 0.f};
    for (int k0 = 0; k0 < K; k0 += 32) {
        {
            float4 a = *(const float4*)(A + (size_t)(m0 + lr) * lda + k0 + lc);
            As[lr][lc] = a.x; As[lr][lc + 1] = a.y;
            As[lr][lc + 2] = a.z; As[lr][lc + 3] = a.w;
        }
        {
            int kk = k0 + lc;
            if (KCL) kk = min(kk, kcl);
            float4 w = *(const float4*)(W + (size_t)(n0 + lr) * ldw + kk);
            Ws[lr][lc] = w.x; Ws[lr][lc + 1] = w.y;
            Ws[lr][lc + 2] = w.z; Ws[lr][lc + 3] = w.w;
        }
        __syncthreads();
#pragma unroll
        for (int kk = 0; kk < 32; ++kk) {
            float wv = Ws[tx][kk];
#pragma unroll
            for (int i = 0; i < 4; ++i)
                acc[i] += As[ty + 8 * i][kk] * wv;
        }
        __syncthreads();
    }
    int n = n0 + tx;
#pragma unroll
    for (int i = 0; i < 4; ++i) {
        int m = m0 + ty + 8 * i;
        C[(size_t)m * ldc + n] = acc[i];
    }
}

// ---------------------------------------------------------------------------
// fuse: fused[b] = [lh[b,0,:], merge(crossp)+out_b, aspq, LN(aro)], zero-pad.
// ---------------------------------------------------------------------------
__global__ void fuse_kernel(const float* __restrict__ lh,
                            const float* __restrict__ crossp,
                            const float* __restrict__ out_b,
                            const float* __restrict__ aspq,
                            const float* __restrict__ aro_f,
                            const float* __restrict__ ln_g,
                            const float* __restrict__ ln_b,
                            float* __restrict__ fused) {
    int b = blockIdx.x, t = threadIdx.x;
    float* fb = fused + (size_t)b * FPAD;
    const float* lhb = lh + (size_t)b * S * H;
    for (int i = t; i < H; i += 256) {
        float cr = out_b[i];
#pragma unroll
        for (int z = 0; z < 6; ++z) cr += crossp[(size_t)z * (B * H) + b * H + i];
        fb[i]         = lhb[i];
        fb[H + i]     = cr;
        fb[2 * H + i] = aspq[b * H + i];
    }
    for (int i = t; i < FPAD - FUSED; i += 256) fb[FUSED + i] = 0.f;
    if (t < 8) {
        const float* af = aro_f + b * 8;
        float mu = 0.f;
#pragma unroll
        for (int j = 0; j < 8; ++j) mu += af[j];
        mu *= 0.125f;
        float var = 0.f;
#pragma unroll
        for (int j = 0; j < 8; ++j) { float d = af[j] - mu; var += d * d; }
        var *= 0.125f;
        fb[3 * H + t] = (af[t] - mu) * rsqrtf(var + 1e-5f) * ln_g[t] + ln_b[t];
    }
}

// ---------------------------------------------------------------------------
// mlp2: reduce hdn1 split-K partials + gelu; hdn2; all 8 head outputs.
// ---------------------------------------------------------------------------
__global__ void mlp2_kernel(const float* __restrict__ hdn1p,
                            const float* __restrict__ fusedb,
                            const float* __restrict__ va_b1,
                            const float* __restrict__ va_w2,
                            const float* __restrict__ va_b2,
                            const float* __restrict__ va_w3,
                            const float* __restrict__ va_b3,
                            const float* __restrict__ pol_w,
                            const float* __restrict__ pol_b,
                            const float* __restrict__ aro_w,
                            const float* __restrict__ aro_b,
                            float* __restrict__ out) {
    int b = blockIdx.x, t = threadIdx.x;
    __shared__ float hs[512];
    __shared__ float h2[128];
    for (int n = t; n < 512; n += 256) {
        float sacc = 0.f;
#pragma unroll
        for (int z = 0; z < KSPLIT; ++z)
            sacc += hdn1p[(size_t)z * (B * 512) + b * 512 + n];
        sacc += va_b1[n];
        hs[n] = 0.5f * sacc * (1.0f + erff(sacc * GELU_C));
    }
    __syncthreads();
    int wave = t >> 6, lane = t & 63;
    for (int i = 0; i < 32; ++i) {
        int n = wave * 32 + i;
        float a = 0.f;
#pragma unroll
        for (int j = 0; j < 8; ++j) {
            int k = lane + 64 * j;
            a += hs[k] * va_w2[(size_t)n * 512 + k];
        }
        for (int off = 32; off; off >>= 1) a += __shfl_xor(a, off);
        if (lane == 0) {
            float x = a + va_b2[n];
            h2[n] = 0.5f * x * (1.0f + erff(x * GELU_C));
        }
    }
    __syncthreads();
    const float* fb = fusedb + (size_t)b * FPAD;
    for (int oi = 0; oi < 2; ++oi) {
        int o = wave * 2 + oi;
        float acc = 0.f, bia;
        float* dst;
        if (o < 2) {
            for (int k = lane; k < 128; k += 64) acc += h2[k] * va_w3[o * 128 + k];
            bia = va_b3[o]; dst = out + b * 2 + o;
        } else if (o < 5) {
            int r = o - 2;
            for (int k = lane; k < FUSED; k += 64) acc += fb[k] * pol_w[(size_t)r * FUSED + k];
            bia = pol_b[r]; dst = out + 256 + b * 3 + r;
        } else {
            int r = o - 5;
            for (int k = lane; k < FUSED; k += 64) acc += fb[k] * aro_w[(size_t)r * FUSED + k];
            bia = aro_b[r]; dst = out + 640 + b * 3 + r;
        }
        for (int off = 32; off; off >>= 1) acc += __shfl_xor(acc, off);
        if (lane == 0) *dst = acc + bia;
    }
}

// ---------------------------------------------------------------------------
extern "C" void kernel_launch(void* const* d_in, const int* in_sizes, int n_in,
                              void* d_out, int out_size, void* d_ws, size_t ws_size,
                              hipStream_t stream) {
    const float* lh    = (const float*)d_in[0];
    const float* aro_f = (const float*)d_in[1];
    const int*   sep1  = (const int*)d_in[2];
    const int*   sep2  = (const int*)d_in[3];
    const float* in_w  = (const float*)d_in[4];
    const float* in_b  = (const float*)d_in[5];
    const float* out_w = (const float*)d_in[6];
    const float* out_b = (const float*)d_in[7];
    const float* ln_g  = (const float*)d_in[8];
    const float* ln_b  = (const float*)d_in[9];
    const float* va_w1 = (const float*)d_in[10];
    const float* va_b1 = (const float*)d_in[11];
    const float* va_w2 = (const float*)d_in[12];
    const float* va_b2 = (const float*)d_in[13];
    const float* va_w3 = (const float*)d_in[14];
    const float* va_b3 = (const float*)d_in[15];
    const float* pol_w = (const float*)d_in[16];
    const float* pol_b = (const float*)d_in[17];
    const float* aro_w = (const float*)d_in[18];
    const float* aro_b = (const float*)d_in[19];
    float* out = (float*)d_out;

    float* ws = (float*)d_ws;
    float* aspp   = ws;                          // ASL*B*H
    float* aspq   = aspp + ASL * B * H;          // B*H
    float* Ubuf   = aspq + B * H;                // B*NH*H
    float* Opb    = Ubuf + B * NH * H;           // NSL*B*NH*H
    float* mlbuf  = Opb + (size_t)NSL * B * NH * H;  // NSL*B*NH*2
    float* ctx    = mlbuf + NSL * B * NH * 2;    // B*H
    float* crossp = ctx + B * H;                 // 6*B*H
    float* fusedb = crossp + 6 * B * H;          // B*FPAD
    float* hdn1p  = fusedb + B * FPAD;           // 19*B*512

    const float* wq = in_w;
    const float* wk = in_w + H * H;
    const float* wv = in_w + 2 * H * H;
    const float* bq = in_b;
    const float* bv = in_b + 2 * H;

    // 1) asp_query partials
    aspq_part_kernel<<<dim3(B, ASL), 192, 0, stream>>>(lh, sep1, sep2, aspp);
    // 2) qu: merge + q + U
    qu_kernel<<<dim3(B, NH), 256, 0, stream>>>(aspp, sep1, sep2, wq, bq, wk,
                                               aspq, Ubuf);
    // 3) flash (wave-per-head)
    flash_kernel<<<dim3(B, NSL), 512, 0, stream>>>(lh, Ubuf, sep1, Opb, mlbuf);
    // 4) mergectx
    mergectx_kernel<<<dim3(B, NH), 256, 0, stream>>>(Opb, mlbuf, wv, bv, ctx);
    // 5) cross partials = ctx @ out_w.T : split-K 6x128 (merged in fuse)
    gemm_kernel<3, false><<<dim3(24, 4, 6), 256, 0, stream>>>(
        ctx, H, KCHUNK, out_w, H, KCHUNK, crossp, H, B * H, B, H, KCHUNK, 0);
    // 6) fused assembly (+cross merge, +LN, +pad)
    fuse_kernel<<<B, 256, 0, stream>>>(lh, crossp, out_b, aspq, aro_f,
                                       ln_g, ln_b, fusedb);
    // 7) hdn1 split-K partials (19 x 128)
    gemm_kernel<4, true><<<dim3(16, 4, KSPLIT), 256, 0, stream>>>(
        fusedb, FPAD, KCHUNK, va_w1, FUSED, KCHUNK,
        hdn1p, 512, B * 512, B, 512, KCHUNK, FUSED - 4);
    // 8) mlp2: reduce+gelu + hdn2 + heads
    mlp2_kernel<<<B, 256, 0, stream>>>(hdn1p, fusedb, va_b1, va_w2, va_b2,
                                       va_w3, va_b3, pol_w, pol_b,
                                       aro_w, aro_b, out);
}